// Round 1
// baseline (1738.044 us; speedup 1.0000x reference)
//
#include <hip/hip_runtime.h>
#include <hip/hip_bf16.h>
#include <math.h>

#define BB 8
#define NN 4096
#define NIN 64
#define NOUTF 128
#define KNB 32
#define MM 1024
#define DIM 68
#define CAP 320

// ---------------------------------------------------------------------------
// Kernel 1: farthest point sampling. One block per batch, serial over M steps.
// Must match numpy f32 arithmetic bit-exactly: no FMA contraction, left-to-
// right sum (dx*dx + dy*dy) + dz*dz, argmax first-occurrence tie-break.
// ---------------------------------------------------------------------------
__global__ __launch_bounds__(512) void fps_kernel(
    const float* __restrict__ pos,
    int* __restrict__ idx_ws, float* __restrict__ pos_s_ws,
    float* __restrict__ out_pos_s, float* __restrict__ out_idx)
{
    __shared__ float px[NN], py[NN], pz[NN];
    __shared__ float redV[8];
    __shared__ int   redI[8];

    const int b   = blockIdx.x;
    const int tid = threadIdx.x;
    const int wv  = tid >> 6, lane = tid & 63;
    const float* pb = pos + (size_t)b * NN * 3;

    float X[8], Y[8], Z[8], D[8];
#pragma unroll
    for (int k = 0; k < 8; ++k) {
        int p = k * 512 + tid;
        float vx = pb[p * 3 + 0];
        float vy = pb[p * 3 + 1];
        float vz = pb[p * 3 + 2];
        X[k] = vx; Y[k] = vy; Z[k] = vz; D[k] = INFINITY;
        px[p] = vx; py[p] = vy; pz[p] = vz;
    }
    __syncthreads();

    int last = 0;
    for (int t = 0; t < MM; ++t) {
        // emit current sample
        if (tid == 0) {
            idx_ws[b * MM + t] = last;
            out_idx[b * MM + t] = (float)last;
            float lx = px[last], ly = py[last], lz = pz[last];
            pos_s_ws[(b * MM + t) * 3 + 0] = lx;
            pos_s_ws[(b * MM + t) * 3 + 1] = ly;
            pos_s_ws[(b * MM + t) * 3 + 2] = lz;
            out_pos_s[(b * MM + t) * 3 + 0] = lx;
            out_pos_s[(b * MM + t) * 3 + 1] = ly;
            out_pos_s[(b * MM + t) * 3 + 2] = lz;
        }
        float lx = px[last], ly = py[last], lz = pz[last];

        float bv = -INFINITY; int bi = 0x7fffffff;
#pragma unroll
        for (int k = 0; k < 8; ++k) {
            float dx = __fsub_rn(X[k], lx);
            float dy = __fsub_rn(Y[k], ly);
            float dz = __fsub_rn(Z[k], lz);
            float s  = __fadd_rn(__fadd_rn(__fmul_rn(dx, dx), __fmul_rn(dy, dy)),
                                 __fmul_rn(dz, dz));
            float nd = fminf(D[k], s);
            D[k] = nd;
            if (nd > bv) { bv = nd; bi = k * 512 + tid; }  // k ascending => first max kept
        }
        // wave-level lex-max reduce (max value, then min index)
#pragma unroll
        for (int off = 1; off < 64; off <<= 1) {
            float ov = __shfl_xor(bv, off);
            int   oi = __shfl_xor(bi, off);
            if (ov > bv || (ov == bv && oi < bi)) { bv = ov; bi = oi; }
        }
        __syncthreads();   // WAR protection for red arrays
        if (lane == 0) { redV[wv] = bv; redI[wv] = bi; }
        __syncthreads();
        float wbv = redV[0]; int wbi = redI[0];
#pragma unroll
        for (int w = 1; w < 8; ++w) {
            float ov = redV[w]; int oi = redI[w];
            if (ov > wbv || (ov == wbv && oi < wbi)) { wbv = ov; wbi = oi; }
        }
        last = wbi;
    }
}

// ---------------------------------------------------------------------------
// Kernel 2: radius search + exact K-smallest selection. One wave per center.
// Selection by (d2, idx) lexicographic rank == lax.top_k stable semantics.
// ---------------------------------------------------------------------------
__global__ __launch_bounds__(256) void radius_kernel(
    const float* __restrict__ pos,
    const float* __restrict__ pos_s_ws,
    int* __restrict__ nbr_ws, int* __restrict__ nvalid_ws)
{
    __shared__ float d2L[4][CAP];
    __shared__ int   idL[4][CAP];
    __shared__ int   cntL[4];

    const int wv = threadIdx.x >> 6, lane = threadIdx.x & 63;
    const int c = blockIdx.x * 4 + wv;
    const int b = c >> 10;
    const float RSQ = 0.0225f;

    if (lane == 0) cntL[wv] = 0;
    // per-wave LDS ops are issue-ordered; no barrier needed (list is wave-private)

    float cx = pos_s_ws[c * 3 + 0];
    float cy = pos_s_ws[c * 3 + 1];
    float cz = pos_s_ws[c * 3 + 2];
    const float* pb = pos + (size_t)b * NN * 3;

    for (int it = 0; it < NN / 64; ++it) {
        int p = it * 64 + lane;
        float dx = __fsub_rn(cx, pb[p * 3 + 0]);
        float dy = __fsub_rn(cy, pb[p * 3 + 1]);
        float dz = __fsub_rn(cz, pb[p * 3 + 2]);
        float d2 = __fadd_rn(__fadd_rn(__fmul_rn(dx, dx), __fmul_rn(dy, dy)),
                             __fmul_rn(dz, dz));
        if (d2 <= RSQ) {
            int slot = atomicAdd(&cntL[wv], 1);
            if (slot < CAP) { d2L[wv][slot] = d2; idL[wv][slot] = p; }
        }
    }
    int n = cntL[wv];
    if (n > CAP) n = CAP;

    if (n <= KNB) {
        if (lane == 0) nvalid_ws[c] = n;
        if (lane < n) nbr_ws[c * KNB + lane] = idL[wv][lane];
    } else {
        if (lane == 0) nvalid_ws[c] = KNB;
        for (int a = lane; a < n; a += 64) {
            float da = d2L[wv][a]; int ia = idL[wv][a];
            int r = 0;
            for (int jj = 0; jj < n; ++jj) {
                float dj = d2L[wv][jj]; int ij = idL[wv][jj];
                r += (dj < da || (dj == da && ij < ia)) ? 1 : 0;
            }
            if (r < KNB) nbr_ws[c * KNB + r] = ia;
        }
    }
}

// ---------------------------------------------------------------------------
// Kernel 3: message build (x_j ++ ppf) -> 68x68 MLP x2 -> masked max-agg ->
// 68x128 output matvec. Block = 2 centers (64 edges), weights in LDS.
// ---------------------------------------------------------------------------
__device__ __forceinline__ float angle3(float ax, float ay, float az,
                                        float bx, float by, float bz)
{
    float cx = ay * bz - az * by;
    float cy = az * bx - ax * bz;
    float cz = ax * by - ay * bx;
    float cn = sqrtf(cx * cx + cy * cy + cz * cz);
    float dt = ax * bx + ay * by + az * bz;
    return atan2f(cn, dt);
}

__device__ __forceinline__ void layer_pass(const float* __restrict__ inL,
                                           const float* __restrict__ Ws,
                                           const float* __restrict__ bs,
                                           float* __restrict__ outL, int t)
{
    const int e = t & 63, wvi = t >> 6;
    for (int jg = wvi; jg < 17; jg += 4) {
        float ax = bs[jg * 4 + 0];
        float ay = bs[jg * 4 + 1];
        float az = bs[jg * 4 + 2];
        float aw = bs[jg * 4 + 3];
#pragma unroll 4
        for (int i = 0; i < DIM; ++i) {
            float m = inL[e * 69 + i];
            const float4 w = *reinterpret_cast<const float4*>(Ws + i * DIM + jg * 4);
            ax = fmaf(m, w.x, ax);
            ay = fmaf(m, w.y, ay);
            az = fmaf(m, w.z, az);
            aw = fmaf(m, w.w, aw);
        }
        outL[e * 69 + jg * 4 + 0] = fmaxf(ax, 0.0f);
        outL[e * 69 + jg * 4 + 1] = fmaxf(ay, 0.0f);
        outL[e * 69 + jg * 4 + 2] = fmaxf(az, 0.0f);
        outL[e * 69 + jg * 4 + 3] = fmaxf(aw, 0.0f);
    }
}

__global__ __launch_bounds__(256) void mlp_kernel(
    const float* __restrict__ x, const float* __restrict__ pos,
    const float* __restrict__ norm,
    const float* __restrict__ W1, const float* __restrict__ b1,
    const float* __restrict__ W2, const float* __restrict__ b2,
    const float* __restrict__ W3, const float* __restrict__ b3,
    const int* __restrict__ idx_ws, const float* __restrict__ pos_s_ws,
    const int* __restrict__ nbr_ws, const int* __restrict__ nvalid_ws,
    float* __restrict__ out)
{
    __shared__ alignas(16) float W1s[DIM * DIM];
    __shared__ alignas(16) float W2s[DIM * DIM];
    __shared__ float b1s[DIM], b2s[DIM];
    __shared__ float msgL[64 * 69];   // msg, later reused as h2
    __shared__ float h1L[64 * 69];
    __shared__ float aggL[2 * DIM];
    __shared__ int   nvL[2], jLs[64];

    const int t = threadIdx.x;
    const int cg0 = blockIdx.x * 2;

    for (int u = t; u < DIM * DIM; u += 256) { W1s[u] = W1[u]; W2s[u] = W2[u]; }
    if (t < DIM) { b1s[t] = b1[t]; b2s[t] = b2[t]; }
    if (t < 2) nvL[t] = min(nvalid_ws[cg0 + t], KNB);
    __syncthreads();

    const int e = t & 63, fc = t >> 6;
    const int lc = e >> 5, slot = e & 31;
    const int c = cg0 + lc;
    const int b = c >> 10;

    if (fc == 0) {
        int nv = nvL[lc];
        jLs[e] = (slot < nv) ? nbr_ws[c * KNB + slot] : 0;
    }
    __syncthreads();

    const int j = jLs[e];
    // gather x_j (each thread: 16 features of its edge)
    {
        const float* xj = x + ((size_t)b * NN + j) * NIN + fc * 16;
#pragma unroll
        for (int r = 0; r < 4; ++r) {
            float4 v = *reinterpret_cast<const float4*>(xj + r * 4);
            msgL[e * 69 + fc * 16 + r * 4 + 0] = v.x;
            msgL[e * 69 + fc * 16 + r * 4 + 1] = v.y;
            msgL[e * 69 + fc * 16 + r * 4 + 2] = v.z;
            msgL[e * 69 + fc * 16 + r * 4 + 3] = v.w;
        }
    }
    // point-pair features (one thread per edge)
    if (fc == 0) {
        float pix = pos_s_ws[c * 3 + 0];
        float piy = pos_s_ws[c * 3 + 1];
        float piz = pos_s_ws[c * 3 + 2];
        int ic = idx_ws[c];
        const float* pj_ = pos  + ((size_t)b * NN + j) * 3;
        const float* nj_ = norm + ((size_t)b * NN + j) * 3;
        const float* ni_ = norm + ((size_t)b * NN + ic) * 3;
        float dx = pj_[0] - pix, dy = pj_[1] - piy, dz = pj_[2] - piz;
        float nix = ni_[0], niy = ni_[1], niz = ni_[2];
        float njx = nj_[0], njy = nj_[1], njz = nj_[2];
        msgL[e * 69 + 64] = sqrtf(dx * dx + dy * dy + dz * dz);
        msgL[e * 69 + 65] = angle3(nix, niy, niz, dx, dy, dz);
        msgL[e * 69 + 66] = angle3(njx, njy, njz, dx, dy, dz);
        msgL[e * 69 + 67] = angle3(nix, niy, niz, njx, njy, njz);
    }
    __syncthreads();

    layer_pass(msgL, W1s, b1s, h1L, t);
    __syncthreads();
    layer_pass(h1L, W2s, b2s, msgL, t);   // h2 -> msgL
    __syncthreads();

    // masked max aggregation over valid slots
    if (t < 2 * DIM) {
        int cc = t / DIM, jf = t % DIM;
        int nv = nvL[cc];
        float v = -INFINITY;
        for (int s = 0; s < nv; ++s)
            v = fmaxf(v, msgL[(cc * 32 + s) * 69 + jf]);
        aggL[cc * DIM + jf] = v;
    }
    __syncthreads();

    // out = relu(agg @ W3 + b3)
    {
        int cc = t >> 7, o = t & 127;
        int cgl = cg0 + cc;
        float acc = b3[o];
#pragma unroll 4
        for (int i = 0; i < DIM; ++i)
            acc = fmaf(aggL[cc * DIM + i], W3[i * NOUTF + o], acc);
        out[(size_t)cgl * NOUTF + o] = fmaxf(acc, 0.0f);
    }
}

// ---------------------------------------------------------------------------
extern "C" void kernel_launch(void* const* d_in, const int* in_sizes, int n_in,
                              void* d_out, int out_size, void* d_ws, size_t ws_size,
                              hipStream_t stream)
{
    const float* x    = (const float*)d_in[0];
    const float* pos  = (const float*)d_in[1];
    const float* norm = (const float*)d_in[2];
    // d_in[3] = batch (unused, implicit in layout)
    const float* W1 = (const float*)d_in[4];
    const float* b1 = (const float*)d_in[5];
    const float* W2 = (const float*)d_in[6];
    const float* b2 = (const float*)d_in[7];
    const float* W3 = (const float*)d_in[8];
    const float* b3 = (const float*)d_in[9];

    float* out       = (float*)d_out;                       // [B*M*128]
    float* out_pos_s = out + (size_t)BB * MM * NOUTF;       // [B*M*3]
    float* out_idx   = out_pos_s + (size_t)BB * MM * 3;     // [B*M]

    char* ws = (char*)d_ws;
    int*   idx_ws    = (int*)ws;                                    // B*M
    float* pos_s_ws  = (float*)(ws + 32768);                        // B*M*3
    int*   nbr_ws    = (int*)(ws + 131072);                         // B*M*K
    int*   nvalid_ws = (int*)(ws + 131072 + (size_t)BB * MM * KNB * 4);

    fps_kernel<<<dim3(BB), dim3(512), 0, stream>>>(pos, idx_ws, pos_s_ws,
                                                   out_pos_s, out_idx);
    radius_kernel<<<dim3((BB * MM) / 4), dim3(256), 0, stream>>>(pos, pos_s_ws,
                                                                 nbr_ws, nvalid_ws);
    mlp_kernel<<<dim3((BB * MM) / 2), dim3(256), 0, stream>>>(
        x, pos, norm, W1, b1, W2, b2, W3, b3,
        idx_ws, pos_s_ws, nbr_ws, nvalid_ws, out);
}

// Round 2
// 1610.624 us; speedup vs baseline: 1.0791x; 1.0791x over previous
//
#include <hip/hip_runtime.h>
#include <hip/hip_bf16.h>
#include <math.h>

#define BB 8
#define NN 4096
#define NIN 64
#define NOUTF 128
#define KNB 32
#define MM 1024
#define DIM 68
#define CAP 320

typedef float f32x2 __attribute__((ext_vector_type(2)));

// ---------------------------------------------------------------------------
// Kernel 1: farthest point sampling. One block per batch, serial over M steps.
// Exact-match constraints: no FMA contraction, (dx*dx+dy*dy)+dz*dz order,
// argmax = first occurrence (max value, then min index).
// 256 threads x 16 points, coords carried in registers through the reduce.
// ---------------------------------------------------------------------------
__global__ __launch_bounds__(256) void fps_kernel(
    const float* __restrict__ pos,
    int* __restrict__ idx_ws, float* __restrict__ pos_s_ws,
    float* __restrict__ out_pos_s, float* __restrict__ out_idx)
{
#pragma clang fp contract(off)
    __shared__ float4 redP[2][4];   // {x, y, z, val} per wave, double-buffered
    __shared__ int    redN[2][4];   // idx per wave

    const int b   = blockIdx.x;
    const int tid = threadIdx.x;
    const int wv  = tid >> 6;
    const float* pb = pos + (size_t)b * NN * 3;

    // 16 points per thread, packed in f32x2 pairs: X[j].x <-> k=2j, .y <-> k=2j+1,
    // global point index p = k*256 + tid.
    f32x2 X[8], Y[8], Z[8], D[8];
#pragma unroll
    for (int j = 0; j < 8; ++j) {
        int pA = (2 * j) * 256 + tid;
        int pB = pA + 256;
        X[j].x = pb[pA * 3 + 0]; X[j].y = pb[pB * 3 + 0];
        Y[j].x = pb[pA * 3 + 1]; Y[j].y = pb[pB * 3 + 1];
        Z[j].x = pb[pA * 3 + 2]; Z[j].y = pb[pB * 3 + 2];
        D[j].x = INFINITY;       D[j].y = INFINITY;
    }

    int   last = 0;
    float lx = pb[0], ly = pb[1], lz = pb[2];

    for (int t = 0; t < MM; ++t) {
        // emit current sample from registers (no LDS dependency)
        if (tid == 0) {
            idx_ws[b * MM + t]  = last;
            out_idx[b * MM + t] = (float)last;
            pos_s_ws[(b * MM + t) * 3 + 0] = lx;
            pos_s_ws[(b * MM + t) * 3 + 1] = ly;
            pos_s_ws[(b * MM + t) * 3 + 2] = lz;
            out_pos_s[(b * MM + t) * 3 + 0] = lx;
            out_pos_s[(b * MM + t) * 3 + 1] = ly;
            out_pos_s[(b * MM + t) * 3 + 2] = lz;
        }

        f32x2 lx2; lx2.x = lx; lx2.y = lx;
        f32x2 ly2; ly2.x = ly; ly2.y = ly;
        f32x2 lz2; lz2.x = lz; lz2.y = lz;

        float bv = -INFINITY;
        int   bi = 0x7fffffff;
#pragma unroll
        for (int j = 0; j < 8; ++j) {
            f32x2 dx = X[j] - lx2;
            f32x2 dy = Y[j] - ly2;
            f32x2 dz = Z[j] - lz2;
            f32x2 s  = (dx * dx + dy * dy) + dz * dz;   // contract off => exact
            float n0 = fminf(D[j].x, s.x);
            float n1 = fminf(D[j].y, s.y);
            D[j].x = n0; D[j].y = n1;
            if (n0 > bv) { bv = n0; bi = (2 * j) * 256 + tid; }
            if (n1 > bv) { bv = n1; bi = (2 * j + 1) * 256 + tid; }
        }

        // packed key: max dist, then min index (keys unique since idx unique)
        unsigned long long key =
            ((unsigned long long)__float_as_uint(bv) << 32) | (unsigned)(~bi);
        unsigned long long rkey = key;
#pragma unroll
        for (int off = 1; off < 64; off <<= 1) {
            unsigned long long o =
                (unsigned long long)__shfl_xor((long long)rkey, off);
            if (o > rkey) rkey = o;
        }

        const int p_ = t & 1;
        if (rkey == key) {
            // this wave's winner lane: extract coords of point bi from registers
            int k = bi >> 8;       // 0..15
            int j = k >> 1;        // 0..7
            f32x2 xa = (j & 1) ? X[1] : X[0];
            f32x2 xb = (j & 1) ? X[3] : X[2];
            f32x2 xc = (j & 1) ? X[5] : X[4];
            f32x2 xd = (j & 1) ? X[7] : X[6];
            f32x2 xe = (j & 2) ? xb : xa;
            f32x2 xf = (j & 2) ? xd : xc;
            f32x2 xg = (j & 4) ? xf : xe;
            float bx = (k & 1) ? xg.y : xg.x;

            f32x2 ya = (j & 1) ? Y[1] : Y[0];
            f32x2 yb = (j & 1) ? Y[3] : Y[2];
            f32x2 yc = (j & 1) ? Y[5] : Y[4];
            f32x2 yd = (j & 1) ? Y[7] : Y[6];
            f32x2 ye = (j & 2) ? yb : ya;
            f32x2 yf = (j & 2) ? yd : yc;
            f32x2 yg = (j & 4) ? yf : ye;
            float by = (k & 1) ? yg.y : yg.x;

            f32x2 za = (j & 1) ? Z[1] : Z[0];
            f32x2 zb = (j & 1) ? Z[3] : Z[2];
            f32x2 zc = (j & 1) ? Z[5] : Z[4];
            f32x2 zd = (j & 1) ? Z[7] : Z[6];
            f32x2 ze = (j & 2) ? zb : za;
            f32x2 zf = (j & 2) ? zd : zc;
            f32x2 zg = (j & 4) ? zf : ze;
            float bz = (k & 1) ? zg.y : zg.x;

            redP[p_][wv] = make_float4(bx, by, bz, bv);
            redN[p_][wv] = bi;
        }
        __syncthreads();   // single barrier per iteration (double-buffered)

        float4 e0 = redP[p_][0], e1 = redP[p_][1], e2 = redP[p_][2], e3 = redP[p_][3];
        int    i0 = redN[p_][0], i1 = redN[p_][1], i2 = redN[p_][2], i3 = redN[p_][3];

        float cv = e0.w; int ci = i0;
        float cx = e0.x, cy = e0.y, cz = e0.z;
        {
            bool bt = (e1.w > cv) || (e1.w == cv && i1 < ci);
            cv = bt ? e1.w : cv; ci = bt ? i1 : ci;
            cx = bt ? e1.x : cx; cy = bt ? e1.y : cy; cz = bt ? e1.z : cz;
        }
        {
            bool bt = (e2.w > cv) || (e2.w == cv && i2 < ci);
            cv = bt ? e2.w : cv; ci = bt ? i2 : ci;
            cx = bt ? e2.x : cx; cy = bt ? e2.y : cy; cz = bt ? e2.z : cz;
        }
        {
            bool bt = (e3.w > cv) || (e3.w == cv && i3 < ci);
            cv = bt ? e3.w : cv; ci = bt ? i3 : ci;
            cx = bt ? e3.x : cx; cy = bt ? e3.y : cy; cz = bt ? e3.z : cz;
        }
        last = ci; lx = cx; ly = cy; lz = cz;
    }
}

// ---------------------------------------------------------------------------
// Kernel 2: radius search + exact K-smallest selection. One wave per center.
// ---------------------------------------------------------------------------
__global__ __launch_bounds__(256) void radius_kernel(
    const float* __restrict__ pos,
    const float* __restrict__ pos_s_ws,
    int* __restrict__ nbr_ws, int* __restrict__ nvalid_ws)
{
    __shared__ float d2L[4][CAP];
    __shared__ int   idL[4][CAP];
    __shared__ int   cntL[4];

    const int wv = threadIdx.x >> 6, lane = threadIdx.x & 63;
    const int c = blockIdx.x * 4 + wv;
    const int b = c >> 10;
    const float RSQ = 0.0225f;

    if (lane == 0) cntL[wv] = 0;

    float cx = pos_s_ws[c * 3 + 0];
    float cy = pos_s_ws[c * 3 + 1];
    float cz = pos_s_ws[c * 3 + 2];
    const float* pb = pos + (size_t)b * NN * 3;

    for (int it = 0; it < NN / 64; ++it) {
        int p = it * 64 + lane;
        float dx = __fsub_rn(cx, pb[p * 3 + 0]);
        float dy = __fsub_rn(cy, pb[p * 3 + 1]);
        float dz = __fsub_rn(cz, pb[p * 3 + 2]);
        float d2 = __fadd_rn(__fadd_rn(__fmul_rn(dx, dx), __fmul_rn(dy, dy)),
                             __fmul_rn(dz, dz));
        if (d2 <= RSQ) {
            int slot = atomicAdd(&cntL[wv], 1);
            if (slot < CAP) { d2L[wv][slot] = d2; idL[wv][slot] = p; }
        }
    }
    int n = cntL[wv];
    if (n > CAP) n = CAP;

    if (n <= KNB) {
        if (lane == 0) nvalid_ws[c] = n;
        if (lane < n) nbr_ws[c * KNB + lane] = idL[wv][lane];
    } else {
        if (lane == 0) nvalid_ws[c] = KNB;
        for (int a = lane; a < n; a += 64) {
            float da = d2L[wv][a]; int ia = idL[wv][a];
            int r = 0;
            for (int jj = 0; jj < n; ++jj) {
                float dj = d2L[wv][jj]; int ij = idL[wv][jj];
                r += (dj < da || (dj == da && ij < ia)) ? 1 : 0;
            }
            if (r < KNB) nbr_ws[c * KNB + r] = ia;
        }
    }
}

// ---------------------------------------------------------------------------
// Kernel 3: message build (x_j ++ ppf) -> 68x68 MLP x2 -> masked max-agg ->
// 68x128 output matvec. Block = 2 centers (64 edges), weights in LDS.
// ---------------------------------------------------------------------------
__device__ __forceinline__ float angle3(float ax, float ay, float az,
                                        float bx, float by, float bz)
{
    float cx = ay * bz - az * by;
    float cy = az * bx - ax * bz;
    float cz = ax * by - ay * bx;
    float cn = sqrtf(cx * cx + cy * cy + cz * cz);
    float dt = ax * bx + ay * by + az * bz;
    return atan2f(cn, dt);
}

__device__ __forceinline__ void layer_pass(const float* __restrict__ inL,
                                           const float* __restrict__ Ws,
                                           const float* __restrict__ bs,
                                           float* __restrict__ outL, int t)
{
    const int e = t & 63, wvi = t >> 6;
    for (int jg = wvi; jg < 17; jg += 4) {
        float ax = bs[jg * 4 + 0];
        float ay = bs[jg * 4 + 1];
        float az = bs[jg * 4 + 2];
        float aw = bs[jg * 4 + 3];
#pragma unroll 4
        for (int i = 0; i < DIM; ++i) {
            float m = inL[e * 69 + i];
            const float4 w = *reinterpret_cast<const float4*>(Ws + i * DIM + jg * 4);
            ax = fmaf(m, w.x, ax);
            ay = fmaf(m, w.y, ay);
            az = fmaf(m, w.z, az);
            aw = fmaf(m, w.w, aw);
        }
        outL[e * 69 + jg * 4 + 0] = fmaxf(ax, 0.0f);
        outL[e * 69 + jg * 4 + 1] = fmaxf(ay, 0.0f);
        outL[e * 69 + jg * 4 + 2] = fmaxf(az, 0.0f);
        outL[e * 69 + jg * 4 + 3] = fmaxf(aw, 0.0f);
    }
}

__global__ __launch_bounds__(256) void mlp_kernel(
    const float* __restrict__ x, const float* __restrict__ pos,
    const float* __restrict__ norm,
    const float* __restrict__ W1, const float* __restrict__ b1,
    const float* __restrict__ W2, const float* __restrict__ b2,
    const float* __restrict__ W3, const float* __restrict__ b3,
    const int* __restrict__ idx_ws, const float* __restrict__ pos_s_ws,
    const int* __restrict__ nbr_ws, const int* __restrict__ nvalid_ws,
    float* __restrict__ out)
{
    __shared__ alignas(16) float W1s[DIM * DIM];
    __shared__ alignas(16) float W2s[DIM * DIM];
    __shared__ float b1s[DIM], b2s[DIM];
    __shared__ float msgL[64 * 69];   // msg, later reused as h2
    __shared__ float h1L[64 * 69];
    __shared__ float aggL[2 * DIM];
    __shared__ int   nvL[2], jLs[64];

    const int t = threadIdx.x;
    const int cg0 = blockIdx.x * 2;

    for (int u = t; u < DIM * DIM; u += 256) { W1s[u] = W1[u]; W2s[u] = W2[u]; }
    if (t < DIM) { b1s[t] = b1[t]; b2s[t] = b2[t]; }
    if (t < 2) nvL[t] = min(nvalid_ws[cg0 + t], KNB);
    __syncthreads();

    const int e = t & 63, fc = t >> 6;
    const int lc = e >> 5, slot = e & 31;
    const int c = cg0 + lc;
    const int b = c >> 10;

    if (fc == 0) {
        int nv = nvL[lc];
        jLs[e] = (slot < nv) ? nbr_ws[c * KNB + slot] : 0;
    }
    __syncthreads();

    const int j = jLs[e];
    // gather x_j (each thread: 16 features of its edge)
    {
        const float* xj = x + ((size_t)b * NN + j) * NIN + fc * 16;
#pragma unroll
        for (int r = 0; r < 4; ++r) {
            float4 v = *reinterpret_cast<const float4*>(xj + r * 4);
            msgL[e * 69 + fc * 16 + r * 4 + 0] = v.x;
            msgL[e * 69 + fc * 16 + r * 4 + 1] = v.y;
            msgL[e * 69 + fc * 16 + r * 4 + 2] = v.z;
            msgL[e * 69 + fc * 16 + r * 4 + 3] = v.w;
        }
    }
    // point-pair features (one thread per edge)
    if (fc == 0) {
        float pix = pos_s_ws[c * 3 + 0];
        float piy = pos_s_ws[c * 3 + 1];
        float piz = pos_s_ws[c * 3 + 2];
        int ic = idx_ws[c];
        const float* pj_ = pos  + ((size_t)b * NN + j) * 3;
        const float* nj_ = norm + ((size_t)b * NN + j) * 3;
        const float* ni_ = norm + ((size_t)b * NN + ic) * 3;
        float dx = pj_[0] - pix, dy = pj_[1] - piy, dz = pj_[2] - piz;
        float nix = ni_[0], niy = ni_[1], niz = ni_[2];
        float njx = nj_[0], njy = nj_[1], njz = nj_[2];
        msgL[e * 69 + 64] = sqrtf(dx * dx + dy * dy + dz * dz);
        msgL[e * 69 + 65] = angle3(nix, niy, niz, dx, dy, dz);
        msgL[e * 69 + 66] = angle3(njx, njy, njz, dx, dy, dz);
        msgL[e * 69 + 67] = angle3(nix, niy, niz, njx, njy, njz);
    }
    __syncthreads();

    layer_pass(msgL, W1s, b1s, h1L, t);
    __syncthreads();
    layer_pass(h1L, W2s, b2s, msgL, t);   // h2 -> msgL
    __syncthreads();

    // masked max aggregation over valid slots
    if (t < 2 * DIM) {
        int cc = t / DIM, jf = t % DIM;
        int nv = nvL[cc];
        float v = -INFINITY;
        for (int s = 0; s < nv; ++s)
            v = fmaxf(v, msgL[(cc * 32 + s) * 69 + jf]);
        aggL[cc * DIM + jf] = v;
    }
    __syncthreads();

    // out = relu(agg @ W3 + b3)
    {
        int cc = t >> 7, o = t & 127;
        int cgl = cg0 + cc;
        float acc = b3[o];
#pragma unroll 4
        for (int i = 0; i < DIM; ++i)
            acc = fmaf(aggL[cc * DIM + i], W3[i * NOUTF + o], acc);
        out[(size_t)cgl * NOUTF + o] = fmaxf(acc, 0.0f);
    }
}

// ---------------------------------------------------------------------------
extern "C" void kernel_launch(void* const* d_in, const int* in_sizes, int n_in,
                              void* d_out, int out_size, void* d_ws, size_t ws_size,
                              hipStream_t stream)
{
    const float* x    = (const float*)d_in[0];
    const float* pos  = (const float*)d_in[1];
    const float* norm = (const float*)d_in[2];
    // d_in[3] = batch (unused, implicit in layout)
    const float* W1 = (const float*)d_in[4];
    const float* b1 = (const float*)d_in[5];
    const float* W2 = (const float*)d_in[6];
    const float* b2 = (const float*)d_in[7];
    const float* W3 = (const float*)d_in[8];
    const float* b3 = (const float*)d_in[9];

    float* out       = (float*)d_out;                       // [B*M*128]
    float* out_pos_s = out + (size_t)BB * MM * NOUTF;       // [B*M*3]
    float* out_idx   = out_pos_s + (size_t)BB * MM * 3;     // [B*M]

    char* ws = (char*)d_ws;
    int*   idx_ws    = (int*)ws;                                    // B*M
    float* pos_s_ws  = (float*)(ws + 32768);                        // B*M*3
    int*   nbr_ws    = (int*)(ws + 131072);                         // B*M*K
    int*   nvalid_ws = (int*)(ws + 131072 + (size_t)BB * MM * KNB * 4);

    fps_kernel<<<dim3(BB), dim3(256), 0, stream>>>(pos, idx_ws, pos_s_ws,
                                                   out_pos_s, out_idx);
    radius_kernel<<<dim3((BB * MM) / 4), dim3(256), 0, stream>>>(pos, pos_s_ws,
                                                                 nbr_ws, nvalid_ws);
    mlp_kernel<<<dim3((BB * MM) / 2), dim3(256), 0, stream>>>(
        x, pos, norm, W1, b1, W2, b2, W3, b3,
        idx_ws, pos_s_ws, nbr_ws, nvalid_ws, out);
}

// Round 3
// 1195.500 us; speedup vs baseline: 1.4538x; 1.3472x over previous
//
#include <hip/hip_runtime.h>
#include <hip/hip_bf16.h>
#include <math.h>

#define BB 8
#define NN 4096
#define NIN 64
#define NOUTF 128
#define KNB 32
#define MM 1024
#define DIM 68
#define CAP 320

typedef float f32x2 __attribute__((ext_vector_type(2)));

// DPP max-reduce step: v = max(v, lanes-moved-v). CTRL compile-time.
template <int CTRL>
__device__ __forceinline__ float dppmax(float v)
{
    int m = __builtin_amdgcn_update_dpp(__float_as_int(v), __float_as_int(v),
                                        CTRL, 0xF, 0xF, false);
    return fmaxf(v, __int_as_float(m));
}

// ---------------------------------------------------------------------------
// Kernel 1: farthest point sampling. One block per batch, serial over M steps.
// Exact-match constraints: no FMA contraction, (dx*dx+dy*dy)+dz*dz order,
// argmax = first occurrence (max value, then min global index).
// Thread-major point mapping: p = tid*16 + k, so lane order == index order.
// Wave argmax: DPP f32 max-reduce (VALU speed) + ballot + s_ff1.
// ---------------------------------------------------------------------------
__global__ __launch_bounds__(256) void fps_kernel(
    const float* __restrict__ pos,
    int* __restrict__ idx_ws, float* __restrict__ pos_s_ws,
    float* __restrict__ out_pos_s, float* __restrict__ out_idx)
{
#pragma clang fp contract(off)
    __shared__ float4 redP[2][4];   // {x, y, z, val} per wave, double-buffered
    __shared__ int    redN[2][4];   // idx per wave

    const int b    = blockIdx.x;
    const int tid  = threadIdx.x;
    const int wv   = tid >> 6;
    const int lane = tid & 63;
    const float* pb = pos + (size_t)b * NN * 3;

    // 16 consecutive points per thread: p = tid*16 + k.
    // Packed pairs: X[j].x <-> k=2j, X[j].y <-> k=2j+1.
    f32x2 X[8], Y[8], Z[8], D[8];
#pragma unroll
    for (int j = 0; j < 8; ++j) {
        int pA = tid * 16 + 2 * j;
        X[j].x = pb[pA * 3 + 0]; X[j].y = pb[pA * 3 + 3];
        Y[j].x = pb[pA * 3 + 1]; Y[j].y = pb[pA * 3 + 4];
        Z[j].x = pb[pA * 3 + 2]; Z[j].y = pb[pA * 3 + 5];
        D[j].x = INFINITY;       D[j].y = INFINITY;
    }

    int   last = 0;
    float lx = pb[0], ly = pb[1], lz = pb[2];

    for (int t = 0; t < MM; ++t) {
        // emit current sample from registers
        if (tid == 0) {
            idx_ws[b * MM + t]  = last;
            out_idx[b * MM + t] = (float)last;
            pos_s_ws[(b * MM + t) * 3 + 0] = lx;
            pos_s_ws[(b * MM + t) * 3 + 1] = ly;
            pos_s_ws[(b * MM + t) * 3 + 2] = lz;
            out_pos_s[(b * MM + t) * 3 + 0] = lx;
            out_pos_s[(b * MM + t) * 3 + 1] = ly;
            out_pos_s[(b * MM + t) * 3 + 2] = lz;
        }

        f32x2 lx2; lx2.x = lx; lx2.y = lx;
        f32x2 ly2; ly2.x = ly; ly2.y = ly;
        f32x2 lz2; lz2.x = lz; lz2.y = lz;

        float bv = -INFINITY;
        int   kloc = 0;
#pragma unroll
        for (int j = 0; j < 8; ++j) {
            f32x2 dx = X[j] - lx2;
            f32x2 dy = Y[j] - ly2;
            f32x2 dz = Z[j] - lz2;
            f32x2 s  = (dx * dx + dy * dy) + dz * dz;   // contract off => exact
            float n0 = fminf(D[j].x, s.x);
            float n1 = fminf(D[j].y, s.y);
            D[j].x = n0; D[j].y = n1;
            if (n0 > bv) { bv = n0; kloc = 2 * j; }      // ascending k => first max
            if (n1 > bv) { bv = n1; kloc = 2 * j + 1; }
        }

        // extract local-best coords on EVERY lane (overlaps the DPP chain)
        int jj = kloc >> 1;
        f32x2 xa = (jj & 1) ? X[1] : X[0];
        f32x2 xb = (jj & 1) ? X[3] : X[2];
        f32x2 xc = (jj & 1) ? X[5] : X[4];
        f32x2 xd = (jj & 1) ? X[7] : X[6];
        f32x2 xe = (jj & 2) ? xb : xa;
        f32x2 xf = (jj & 2) ? xd : xc;
        f32x2 xg = (jj & 4) ? xf : xe;
        float bx = (kloc & 1) ? xg.y : xg.x;

        f32x2 ya = (jj & 1) ? Y[1] : Y[0];
        f32x2 yb = (jj & 1) ? Y[3] : Y[2];
        f32x2 yc = (jj & 1) ? Y[5] : Y[4];
        f32x2 yd = (jj & 1) ? Y[7] : Y[6];
        f32x2 ye = (jj & 2) ? yb : ya;
        f32x2 yf = (jj & 2) ? yd : yc;
        f32x2 yg = (jj & 4) ? yf : ye;
        float by = (kloc & 1) ? yg.y : yg.x;

        f32x2 za = (jj & 1) ? Z[1] : Z[0];
        f32x2 zb = (jj & 1) ? Z[3] : Z[2];
        f32x2 zc = (jj & 1) ? Z[5] : Z[4];
        f32x2 zd = (jj & 1) ? Z[7] : Z[6];
        f32x2 ze = (jj & 2) ? zb : za;
        f32x2 zf = (jj & 2) ? zd : zc;
        f32x2 zg = (jj & 4) ? zf : ze;
        float bz = (kloc & 1) ? zg.y : zg.x;

        // VALU-speed wave max-reduce: row_shr 1/2/4/8, row_bcast 15/31
        float r = bv;
        r = dppmax<0x111>(r);
        r = dppmax<0x112>(r);
        r = dppmax<0x114>(r);
        r = dppmax<0x118>(r);
        r = dppmax<0x142>(r);
        r = dppmax<0x143>(r);
        float wmax = __int_as_float(__builtin_amdgcn_readlane(__float_as_int(r), 63));

        // winner = lowest lane matching wmax (== smallest global index)
        unsigned long long msk = __ballot(bv == wmax);
        int wl = __ffsll(msk) - 1;

        const int p_ = t & 1;
        if (lane == wl) {
            redP[p_][wv] = make_float4(bx, by, bz, bv);
            redN[p_][wv] = tid * 16 + kloc;
        }
        __syncthreads();   // single barrier per iteration (double-buffered)

        float4 e0 = redP[p_][0], e1 = redP[p_][1], e2 = redP[p_][2], e3 = redP[p_][3];
        int    i0 = redN[p_][0], i1 = redN[p_][1], i2 = redN[p_][2], i3 = redN[p_][3];

        float cv = e0.w; int ci = i0;
        float cx = e0.x, cy = e0.y, cz = e0.z;
        {
            bool bt = (e1.w > cv) || (e1.w == cv && i1 < ci);
            cv = bt ? e1.w : cv; ci = bt ? i1 : ci;
            cx = bt ? e1.x : cx; cy = bt ? e1.y : cy; cz = bt ? e1.z : cz;
        }
        {
            bool bt = (e2.w > cv) || (e2.w == cv && i2 < ci);
            cv = bt ? e2.w : cv; ci = bt ? i2 : ci;
            cx = bt ? e2.x : cx; cy = bt ? e2.y : cy; cz = bt ? e2.z : cz;
        }
        {
            bool bt = (e3.w > cv) || (e3.w == cv && i3 < ci);
            cv = bt ? e3.w : cv; ci = bt ? i3 : ci;
            cx = bt ? e3.x : cx; cy = bt ? e3.y : cy; cz = bt ? e3.z : cz;
        }
        last = ci; lx = cx; ly = cy; lz = cz;
    }
}

// ---------------------------------------------------------------------------
// Kernel 2: radius search + exact K-smallest selection. One wave per center.
// ---------------------------------------------------------------------------
__global__ __launch_bounds__(256) void radius_kernel(
    const float* __restrict__ pos,
    const float* __restrict__ pos_s_ws,
    int* __restrict__ nbr_ws, int* __restrict__ nvalid_ws)
{
    __shared__ float d2L[4][CAP];
    __shared__ int   idL[4][CAP];
    __shared__ int   cntL[4];

    const int wv = threadIdx.x >> 6, lane = threadIdx.x & 63;
    const int c = blockIdx.x * 4 + wv;
    const int b = c >> 10;
    const float RSQ = 0.0225f;

    if (lane == 0) cntL[wv] = 0;

    float cx = pos_s_ws[c * 3 + 0];
    float cy = pos_s_ws[c * 3 + 1];
    float cz = pos_s_ws[c * 3 + 2];
    const float* pb = pos + (size_t)b * NN * 3;

    for (int it = 0; it < NN / 64; ++it) {
        int p = it * 64 + lane;
        float dx = __fsub_rn(cx, pb[p * 3 + 0]);
        float dy = __fsub_rn(cy, pb[p * 3 + 1]);
        float dz = __fsub_rn(cz, pb[p * 3 + 2]);
        float d2 = __fadd_rn(__fadd_rn(__fmul_rn(dx, dx), __fmul_rn(dy, dy)),
                             __fmul_rn(dz, dz));
        if (d2 <= RSQ) {
            int slot = atomicAdd(&cntL[wv], 1);
            if (slot < CAP) { d2L[wv][slot] = d2; idL[wv][slot] = p; }
        }
    }
    int n = cntL[wv];
    if (n > CAP) n = CAP;

    if (n <= KNB) {
        if (lane == 0) nvalid_ws[c] = n;
        if (lane < n) nbr_ws[c * KNB + lane] = idL[wv][lane];
    } else {
        if (lane == 0) nvalid_ws[c] = KNB;
        for (int a = lane; a < n; a += 64) {
            float da = d2L[wv][a]; int ia = idL[wv][a];
            int r = 0;
            for (int jj = 0; jj < n; ++jj) {
                float dj = d2L[wv][jj]; int ij = idL[wv][jj];
                r += (dj < da || (dj == da && ij < ia)) ? 1 : 0;
            }
            if (r < KNB) nbr_ws[c * KNB + r] = ia;
        }
    }
}

// ---------------------------------------------------------------------------
// Kernel 3: message build (x_j ++ ppf) -> 68x68 MLP x2 -> masked max-agg ->
// 68x128 output matvec. Block = 2 centers (64 edges), weights in LDS.
// ---------------------------------------------------------------------------
__device__ __forceinline__ float angle3(float ax, float ay, float az,
                                        float bx, float by, float bz)
{
    float cx = ay * bz - az * by;
    float cy = az * bx - ax * bz;
    float cz = ax * by - ay * bx;
    float cn = sqrtf(cx * cx + cy * cy + cz * cz);
    float dt = ax * bx + ay * by + az * bz;
    return atan2f(cn, dt);
}

__device__ __forceinline__ void layer_pass(const float* __restrict__ inL,
                                           const float* __restrict__ Ws,
                                           const float* __restrict__ bs,
                                           float* __restrict__ outL, int t)
{
    const int e = t & 63, wvi = t >> 6;
    for (int jg = wvi; jg < 17; jg += 4) {
        float ax = bs[jg * 4 + 0];
        float ay = bs[jg * 4 + 1];
        float az = bs[jg * 4 + 2];
        float aw = bs[jg * 4 + 3];
#pragma unroll 4
        for (int i = 0; i < DIM; ++i) {
            float m = inL[e * 69 + i];
            const float4 w = *reinterpret_cast<const float4*>(Ws + i * DIM + jg * 4);
            ax = fmaf(m, w.x, ax);
            ay = fmaf(m, w.y, ay);
            az = fmaf(m, w.z, az);
            aw = fmaf(m, w.w, aw);
        }
        outL[e * 69 + jg * 4 + 0] = fmaxf(ax, 0.0f);
        outL[e * 69 + jg * 4 + 1] = fmaxf(ay, 0.0f);
        outL[e * 69 + jg * 4 + 2] = fmaxf(az, 0.0f);
        outL[e * 69 + jg * 4 + 3] = fmaxf(aw, 0.0f);
    }
}

__global__ __launch_bounds__(256) void mlp_kernel(
    const float* __restrict__ x, const float* __restrict__ pos,
    const float* __restrict__ norm,
    const float* __restrict__ W1, const float* __restrict__ b1,
    const float* __restrict__ W2, const float* __restrict__ b2,
    const float* __restrict__ W3, const float* __restrict__ b3,
    const int* __restrict__ idx_ws, const float* __restrict__ pos_s_ws,
    const int* __restrict__ nbr_ws, const int* __restrict__ nvalid_ws,
    float* __restrict__ out)
{
    __shared__ alignas(16) float W1s[DIM * DIM];
    __shared__ alignas(16) float W2s[DIM * DIM];
    __shared__ float b1s[DIM], b2s[DIM];
    __shared__ float msgL[64 * 69];   // msg, later reused as h2
    __shared__ float h1L[64 * 69];
    __shared__ float aggL[2 * DIM];
    __shared__ int   nvL[2], jLs[64];

    const int t = threadIdx.x;
    const int cg0 = blockIdx.x * 2;

    for (int u = t; u < DIM * DIM; u += 256) { W1s[u] = W1[u]; W2s[u] = W2[u]; }
    if (t < DIM) { b1s[t] = b1[t]; b2s[t] = b2[t]; }
    if (t < 2) nvL[t] = min(nvalid_ws[cg0 + t], KNB);
    __syncthreads();

    const int e = t & 63, fc = t >> 6;
    const int lc = e >> 5, slot = e & 31;
    const int c = cg0 + lc;
    const int b = c >> 10;

    if (fc == 0) {
        int nv = nvL[lc];
        jLs[e] = (slot < nv) ? nbr_ws[c * KNB + slot] : 0;
    }
    __syncthreads();

    const int j = jLs[e];
    // gather x_j (each thread: 16 features of its edge)
    {
        const float* xj = x + ((size_t)b * NN + j) * NIN + fc * 16;
#pragma unroll
        for (int r = 0; r < 4; ++r) {
            float4 v = *reinterpret_cast<const float4*>(xj + r * 4);
            msgL[e * 69 + fc * 16 + r * 4 + 0] = v.x;
            msgL[e * 69 + fc * 16 + r * 4 + 1] = v.y;
            msgL[e * 69 + fc * 16 + r * 4 + 2] = v.z;
            msgL[e * 69 + fc * 16 + r * 4 + 3] = v.w;
        }
    }
    // point-pair features (one thread per edge)
    if (fc == 0) {
        float pix = pos_s_ws[c * 3 + 0];
        float piy = pos_s_ws[c * 3 + 1];
        float piz = pos_s_ws[c * 3 + 2];
        int ic = idx_ws[c];
        const float* pj_ = pos  + ((size_t)b * NN + j) * 3;
        const float* nj_ = norm + ((size_t)b * NN + j) * 3;
        const float* ni_ = norm + ((size_t)b * NN + ic) * 3;
        float dx = pj_[0] - pix, dy = pj_[1] - piy, dz = pj_[2] - piz;
        float nix = ni_[0], niy = ni_[1], niz = ni_[2];
        float njx = nj_[0], njy = nj_[1], njz = nj_[2];
        msgL[e * 69 + 64] = sqrtf(dx * dx + dy * dy + dz * dz);
        msgL[e * 69 + 65] = angle3(nix, niy, niz, dx, dy, dz);
        msgL[e * 69 + 66] = angle3(njx, njy, njz, dx, dy, dz);
        msgL[e * 69 + 67] = angle3(nix, niy, niz, njx, njy, njz);
    }
    __syncthreads();

    layer_pass(msgL, W1s, b1s, h1L, t);
    __syncthreads();
    layer_pass(h1L, W2s, b2s, msgL, t);   // h2 -> msgL
    __syncthreads();

    // masked max aggregation over valid slots
    if (t < 2 * DIM) {
        int cc = t / DIM, jf = t % DIM;
        int nv = nvL[cc];
        float v = -INFINITY;
        for (int s = 0; s < nv; ++s)
            v = fmaxf(v, msgL[(cc * 32 + s) * 69 + jf]);
        aggL[cc * DIM + jf] = v;
    }
    __syncthreads();

    // out = relu(agg @ W3 + b3)
    {
        int cc = t >> 7, o = t & 127;
        int cgl = cg0 + cc;
        float acc = b3[o];
#pragma unroll 4
        for (int i = 0; i < DIM; ++i)
            acc = fmaf(aggL[cc * DIM + i], W3[i * NOUTF + o], acc);
        out[(size_t)cgl * NOUTF + o] = fmaxf(acc, 0.0f);
    }
}

// ---------------------------------------------------------------------------
extern "C" void kernel_launch(void* const* d_in, const int* in_sizes, int n_in,
                              void* d_out, int out_size, void* d_ws, size_t ws_size,
                              hipStream_t stream)
{
    const float* x    = (const float*)d_in[0];
    const float* pos  = (const float*)d_in[1];
    const float* norm = (const float*)d_in[2];
    // d_in[3] = batch (unused, implicit in layout)
    const float* W1 = (const float*)d_in[4];
    const float* b1 = (const float*)d_in[5];
    const float* W2 = (const float*)d_in[6];
    const float* b2 = (const float*)d_in[7];
    const float* W3 = (const float*)d_in[8];
    const float* b3 = (const float*)d_in[9];

    float* out       = (float*)d_out;                       // [B*M*128]
    float* out_pos_s = out + (size_t)BB * MM * NOUTF;       // [B*M*3]
    float* out_idx   = out_pos_s + (size_t)BB * MM * 3;     // [B*M]

    char* ws = (char*)d_ws;
    int*   idx_ws    = (int*)ws;                                    // B*M
    float* pos_s_ws  = (float*)(ws + 32768);                        // B*M*3
    int*   nbr_ws    = (int*)(ws + 131072);                         // B*M*K
    int*   nvalid_ws = (int*)(ws + 131072 + (size_t)BB * MM * KNB * 4);

    fps_kernel<<<dim3(BB), dim3(256), 0, stream>>>(pos, idx_ws, pos_s_ws,
                                                   out_pos_s, out_idx);
    radius_kernel<<<dim3((BB * MM) / 4), dim3(256), 0, stream>>>(pos, pos_s_ws,
                                                                 nbr_ws, nvalid_ws);
    mlp_kernel<<<dim3((BB * MM) / 2), dim3(256), 0, stream>>>(
        x, pos, norm, W1, b1, W2, b2, W3, b3,
        idx_ws, pos_s_ws, nbr_ws, nvalid_ws, out);
}